// Round 15
// baseline (38.421 us; speedup 1.0000x reference)
//
#include <hip/hip_runtime.h>
#include <hip/hip_fp16.h>

#define NG 14
#define NE 16
#define NW 32            // wafers per chunk/block
#define YW 148           // per-wafer y stride in LDS (half units)

typedef __fp16 h2 __attribute__((ext_vector_type(2)));
typedef __fp16 h4 __attribute__((ext_vector_type(4)));
typedef __fp16 h8 __attribute__((ext_vector_type(8)));

__device__ __forceinline__ float hdot4(h4 a, h4 b, float c) {
    const h2 a0 = __builtin_shufflevector(a, a, 0, 1);
    const h2 a1 = __builtin_shufflevector(a, a, 2, 3);
    const h2 b0 = __builtin_shufflevector(b, b, 0, 1);
    const h2 b1 = __builtin_shufflevector(b, b, 2, 3);
    return __builtin_amdgcn_fdot2(a1, b1, __builtin_amdgcn_fdot2(a0, b0, c, false), false);
}

// compile-time-folded zero-padded x access
#define XEL(R,C) (((R) < 0 || (R) > 7 || (C) < 0 || (C) > 7) ? 0.f : xv[(R)&7][(C)&7])

__global__ __launch_bounds__(256, 4) void ae_main(
    const float* __restrict__ x,
    const int*   __restrict__ keys,
    const float* __restrict__ conv_mask,
    const float* __restrict__ enc_conv_w,
    const float* __restrict__ enc_dense_w,
    const float* __restrict__ enc_dense_b,
    const float* __restrict__ dec_dense_w,
    const float* __restrict__ dec_dense_b,
    const float* __restrict__ dec_tconv_w,
    const float* __restrict__ dec_tconv_b,
    const int    N,
    float* __restrict__ out)
{
    const int t = threadIdx.x;
    const int chunk = blockIdx.x / NG;
    const int g = blockIdx.x - chunk * NG;
    const int lane = t & 63, wid = t >> 6;

    __shared__ __attribute__((aligned(16))) __half yt[NW * YW]; // y in fp16 (9.25 KB)
    __shared__ __attribute__((aligned(16))) h2 ews2[640];       // enc w fp16, (pr*8+ch)*20 + o*2+jj
    __shared__ __attribute__((aligned(16))) h2 dws2[512];       // dec w fp16, (p*8+ch)*4 + oo
    __shared__ __attribute__((aligned(16))) h2 wtr2[48];        // tconv w fp16 [tap][hc][chpair]; taps 9..11 = 0
    __shared__ __attribute__((aligned(16))) float wcs[72];      // masked conv w [tap*8+ch]
    __shared__ float dbs[128];                                  // dec bias [p*8+ch]
    __shared__ float ebs[8];
    // in-block binning state
    __shared__ int hist[NE];
    __shared__ unsigned long long segmask[64];  // per-64-key segment match masks (N <= 4096)
    __shared__ int segpre[64];
    __shared__ int sids[NW];
    __shared__ int ebx[2];                      // {expert, window lo}

    // ---- prologue A: histogram of all keys (parallel per block) ----
    if (t < NE) hist[t] = 0;
    if (t < NW) sids[t] = -1;
    __syncthreads();
    for (int i = t; i < N; i += 256) atomicAdd(&hist[keys[i]], 1);
    __syncthreads();
    if (t == 0) {
        int run = 0, e = -1, lo = 0;
        const int base = chunk * NW;
        for (int ee = 0; ee < NE; ++ee) {
            const int padded = (hist[ee] + NW - 1) & ~(NW - 1);
            if (e < 0 && base >= run && base < run + padded) { e = ee; lo = base - run; }
            run += padded;
        }
        ebx[0] = e; ebx[1] = lo;
    }
    __syncthreads();
    const int k = ebx[0];          // expert == weight index
    const int lo = ebx[1];
    if (k < 0) return;             // chunk beyond all padded bins (uniform exit)

    // ---- prologue B: stage weights (loads issue here; latency hides under selection) ----
    const size_t wg1024 = (size_t)(k * NG + g) * 1024;
    {   // ews: thread t <-> (o = t>>5, ch = (t>>2)&7, pr = t&3), 4 floats each
        const float4 w4 = *(const float4*)(enc_dense_w + wg1024 + 4 * t);
        const int o = t >> 5, c2 = (t >> 2) & 7, pr = t & 3;
        const int base = (pr * 8 + c2) * 20 + o * 2;
        ews2[base]     = __builtin_amdgcn_cvt_pkrtz(w4.x, w4.y);
        ews2[base + 1] = __builtin_amdgcn_cvt_pkrtz(w4.z, w4.w);
    }
    if (t < 128) {  // dws: row f = t (= ch*16+p), 8 floats -> 4 h2 (b128 store)
        const float4 a = *(const float4*)(dec_dense_w + wg1024 + 8 * t);
        const float4 b = *(const float4*)(dec_dense_w + wg1024 + 8 * t + 4);
        const int c2 = t >> 4, p = t & 15;
        h2* dst = &dws2[(p * 8 + c2) * 4];
        dst[0] = __builtin_amdgcn_cvt_pkrtz(a.x, a.y);
        dst[1] = __builtin_amdgcn_cvt_pkrtz(a.z, a.w);
        dst[2] = __builtin_amdgcn_cvt_pkrtz(b.x, b.y);
        dst[3] = __builtin_amdgcn_cvt_pkrtz(b.z, b.w);
    } else if (t < 200) {
        const int i = t - 128, c2 = i / 9, tap = i - c2 * 9;
        wcs[tap * 8 + c2] = enc_conv_w[(size_t)k * 1008 + (g * 8 + c2) * 9 + tap] * conv_mask[tap];
    } else if (t < 208) {
        ebs[t - 200] = enc_dense_b[(size_t)k * 112 + g * 8 + (t - 208 + 8)];
    } else if (t < 256) {
        const int i = t - 208, tap = i >> 2, j = i & 3;    // 48 threads: taps 0..11
        h2 v = (h2)(__fp16)0.f;
        if (tap < 9) {
            const float wa = dec_tconv_w[(size_t)k * 1008 + (g * 8 + 2*j) * 9 + tap];
            const float wb = dec_tconv_w[(size_t)k * 1008 + (g * 8 + 2*j + 1) * 9 + tap];
            v = __builtin_amdgcn_cvt_pkrtz(wa, wb);
        }
        wtr2[tap * 4 + j] = v;
    }
    if (t < 128) {
        dbs[(t & 15) * 8 + (t >> 4)] = dec_dense_b[(size_t)k * 1792 + g * 128 + t];
    }

    // ---- prologue C: deterministic ballot-rank selection of this chunk's 32 wafers ----
    for (int it = 0; it * 256 < N; ++it) {
        const int i = it * 256 + t;
        const unsigned long long bm = __ballot(i < N && keys[i] == k);
        if (lane == 0) segmask[it * 4 + wid] = bm;
    }
    __syncthreads();
    if (t < 64) {
        const int nseg = ((N + 255) >> 8) * 4;
        int c = 0;
        if (t < nseg) c = __popcll(segmask[t]);
        int inc = c;
        #pragma unroll
        for (int off = 1; off < 64; off <<= 1) {
            const int v = __shfl_up(inc, off);
            if (lane >= off) inc += v;
        }
        segpre[t] = inc - c;   // exclusive prefix of match counts
    }
    __syncthreads();
    {
        const unsigned long long ltmask = (1ULL << lane) - 1ULL;
        for (int it = 0; it * 256 < N; ++it) {
            const int i = it * 256 + t;
            if (i < N && keys[i] == k) {
                const int s = segpre[it * 4 + wid]
                            + __popcll(segmask[it * 4 + wid] & ltmask) - lo;
                if (s >= 0 && s < NW) sids[s] = i;
            }
        }
    }
    __syncthreads();   // sids + all staged LDS now visible

    const int w = t >> 3, ch = t & 7;
    const int idw = sids[w];
    const int idr = (idw < 0) ? sids[0] : idw;

    // ---- x rows -> registers ----
    const float* xg = x + (size_t)idr * 896 + g * 64;
    float xv[8][8];
    #pragma unroll
    for (int r = 0; r < 8; ++r) {
        const float4 a = *(const float4*)(xg + r * 8);
        const float4 b = *(const float4*)(xg + r * 8 + 4);
        xv[r][0]=a.x; xv[r][1]=a.y; xv[r][2]=a.z; xv[r][3]=a.w;
        xv[r][4]=b.x; xv[r][5]=b.y; xv[r][6]=b.z; xv[r][7]=b.w;
    }

    // ---- P1+P2 fused: conv(7 taps)+ReLU+maxpool -> enc GEMV partials (fdot2) ----
    const float w0 = wcs[0*8+ch], w1 = wcs[1*8+ch], w3 = wcs[3*8+ch], w4 = wcs[4*8+ch],
                w5 = wcs[5*8+ch], w7 = wcs[7*8+ch], w8 = wcs[8*8+ch];
    float part[8] = {0.f,0.f,0.f,0.f,0.f,0.f,0.f,0.f};
    #pragma unroll
    for (int pr = 0; pr < 4; ++pr) {
        float res[4];
        #pragma unroll
        for (int pc = 0; pc < 4; ++pc) {
            float mx = 0.f;
            #pragma unroll
            for (int rl = 0; rl < 2; ++rl) {
                #pragma unroll
                for (int cl = 0; cl < 2; ++cl) {
                    const int ir = 2*pr + rl, jc = 2*pc + cl;
                    const float s = w0*XEL(ir-1,jc-1) + w1*XEL(ir-1,jc)
                                  + w3*XEL(ir,jc-1)  + w4*XEL(ir,jc) + w5*XEL(ir,jc+1)
                                  + w7*XEL(ir+1,jc)  + w8*XEL(ir+1,jc+1);
                    mx = fmaxf(mx, s);
                }
            }
            res[pc] = mx;
        }
        const h2 ra = __builtin_amdgcn_cvt_pkrtz(res[0], res[1]);
        const h2 rb = __builtin_amdgcn_cvt_pkrtz(res[2], res[3]);
        const h2* eb2 = &ews2[(pr * 8 + ch) * 20];
        #pragma unroll
        for (int q = 0; q < 4; ++q) {
            const h8 v = *(const h8*)(eb2 + q * 4);
            const h2 a0 = __builtin_shufflevector(v, v, 0, 1);
            const h2 a1 = __builtin_shufflevector(v, v, 2, 3);
            const h2 b0 = __builtin_shufflevector(v, v, 4, 5);
            const h2 b1 = __builtin_shufflevector(v, v, 6, 7);
            part[2*q]   = __builtin_amdgcn_fdot2(rb, a1, __builtin_amdgcn_fdot2(ra, a0, part[2*q],   false), false);
            part[2*q+1] = __builtin_amdgcn_fdot2(rb, b1, __builtin_amdgcn_fdot2(ra, b0, part[2*q+1], false), false);
        }
    }

    // ---- reduce across the 8 channel lanes; z in registers ----
    float z[8];
    #pragma unroll
    for (int o = 0; o < 8; ++o) {
        float v = part[o];
        v += __shfl_xor(v, 1);
        v += __shfl_xor(v, 2);
        v += __shfl_xor(v, 4);
        z[o] = fmaxf(v + ebs[o], 0.f);
    }
    const h2 z01 = __builtin_amdgcn_cvt_pkrtz(z[0], z[1]);
    const h2 z23 = __builtin_amdgcn_cvt_pkrtz(z[2], z[3]);
    const h2 z45 = __builtin_amdgcn_cvt_pkrtz(z[4], z[5]);
    const h2 z67 = __builtin_amdgcn_cvt_pkrtz(z[6], z[7]);

    // ---- P3: y = relu(decW . z + b) -> LDS fp16 [w][pi*36+pj*8+ch] ----
    __half* yw_ = yt + w * YW;
    #pragma unroll
    for (int p = 0; p < 16; ++p) {
        const h8 v = *(const h8*)(&dws2[(p * 8 + ch) * 4]);
        const h2 v0 = __builtin_shufflevector(v, v, 0, 1);
        const h2 v1 = __builtin_shufflevector(v, v, 2, 3);
        const h2 v2 = __builtin_shufflevector(v, v, 4, 5);
        const h2 v3 = __builtin_shufflevector(v, v, 6, 7);
        float acc = dbs[p * 8 + ch];
        acc = __builtin_amdgcn_fdot2(z01, v0, acc, false);
        acc = __builtin_amdgcn_fdot2(z23, v1, acc, false);
        acc = __builtin_amdgcn_fdot2(z45, v2, acc, false);
        acc = __builtin_amdgcn_fdot2(z67, v3, acc, false);
        yw_[(p >> 2) * 36 + (p & 3) * 8 + ch] = __float2half(fmaxf(acc, 0.f));
    }
    __syncthreads();

    // ---- P4: ConvTranspose2d via fp16 fdot2; thread (w, oi=ch) -> one out row ----
    const int oi = ch;
    int iA, rA, iB, rB;
    if ((oi & 1) == 0) { iA = oi >> 1; rA = 3; iB = 0; rB = 9; }
    else { iA = (oi - 1) >> 1; rA = 6;
           if (oi < 7) { iB = (oi + 1) >> 1; rB = 0; } else { iB = 0; rB = 9; } }
    const float bias = dec_tconv_b[k * NG + g];
    const __fp16* ywh = (const __fp16*)(yt) + w * YW;
    float acc[8] = {0.f,0.f,0.f,0.f,0.f,0.f,0.f,0.f};
    #pragma unroll
    for (int hc = 0; hc < 2; ++hc) {
        const h4 wA0 = *(const h4*)(wtr2 + (rA + 0) * 4 + hc * 2);
        const h4 wA1 = *(const h4*)(wtr2 + (rA + 1) * 4 + hc * 2);
        const h4 wA2 = *(const h4*)(wtr2 + (rA + 2) * 4 + hc * 2);
        const h4 wB0 = *(const h4*)(wtr2 + (rB + 0) * 4 + hc * 2);
        const h4 wB1 = *(const h4*)(wtr2 + (rB + 1) * 4 + hc * 2);
        const h4 wB2 = *(const h4*)(wtr2 + (rB + 2) * 4 + hc * 2);
        h4 yA[4], yB[4];
        #pragma unroll
        for (int j = 0; j < 4; ++j) {
            yA[j] = *(const h4*)(ywh + iA * 36 + j * 8 + hc * 4);
            yB[j] = *(const h4*)(ywh + iB * 36 + j * 8 + hc * 4);
        }
        acc[0] = hdot4(wB1, yB[0], hdot4(wA1, yA[0], acc[0]));
        acc[1] = hdot4(wB0, yB[1], hdot4(wB2, yB[0],
                 hdot4(wA0, yA[1], hdot4(wA2, yA[0], acc[1]))));
        acc[2] = hdot4(wB1, yB[1], hdot4(wA1, yA[1], acc[2]));
        acc[3] = hdot4(wB0, yB[2], hdot4(wB2, yB[1],
                 hdot4(wA0, yA[2], hdot4(wA2, yA[1], acc[3]))));
        acc[4] = hdot4(wB1, yB[2], hdot4(wA1, yA[2], acc[4]));
        acc[5] = hdot4(wB0, yB[3], hdot4(wB2, yB[2],
                 hdot4(wA0, yA[3], hdot4(wA2, yA[2], acc[5]))));
        acc[6] = hdot4(wB1, yB[3], hdot4(wA1, yA[3], acc[6]));
        acc[7] = hdot4(wB2, yB[3], hdot4(wA2, yA[3], acc[7]));
    }
    if (idw >= 0) {
        float* og = out + (size_t)idw * 896 + g * 64 + oi * 8;
        *(float4*)(og)     = make_float4(fmaxf(acc[0]+bias,0.f), fmaxf(acc[1]+bias,0.f),
                                         fmaxf(acc[2]+bias,0.f), fmaxf(acc[3]+bias,0.f));
        *(float4*)(og + 4) = make_float4(fmaxf(acc[4]+bias,0.f), fmaxf(acc[5]+bias,0.f),
                                         fmaxf(acc[6]+bias,0.f), fmaxf(acc[7]+bias,0.f));
    }
}

extern "C" void kernel_launch(void* const* d_in, const int* in_sizes, int n_in,
                              void* d_out, int out_size, void* d_ws, size_t ws_size,
                              hipStream_t stream) {
    const float* x            = (const float*)d_in[0];
    const int*   keys         = (const int*)d_in[1];
    const float* conv_mask    = (const float*)d_in[2];
    const float* enc_conv_w   = (const float*)d_in[3];
    const float* enc_dense_w  = (const float*)d_in[4];
    const float* enc_dense_b  = (const float*)d_in[5];
    const float* dec_dense_w  = (const float*)d_in[6];
    const float* dec_dense_b  = (const float*)d_in[7];
    const float* dec_tconv_w  = (const float*)d_in[8];
    const float* dec_tconv_b  = (const float*)d_in[9];
    float* out = (float*)d_out;

    const int N = in_sizes[0] / (NG * 64);                   // 4096
    const int CHUNKS = (N + NE * (NW - 1)) / NW + 1;         // 144

    ae_main<<<CHUNKS * NG, 256, 0, stream>>>(
        x, keys, conv_mask, enc_conv_w, enc_dense_w, enc_dense_b,
        dec_dense_w, dec_dense_b, dec_tconv_w, dec_tconv_b, N, out);
}

// Round 16
// 27.105 us; speedup vs baseline: 1.4175x; 1.4175x over previous
//
#include <hip/hip_runtime.h>
#include <hip/hip_fp16.h>

#define NG 14
#define NE 16
#define NW 32            // wafers per chunk/block
#define YW 152           // per-wafer y stride in halfs; 304B -> 16B-aligned rows

typedef __fp16 h2 __attribute__((ext_vector_type(2)));
typedef __fp16 h4 __attribute__((ext_vector_type(4)));
typedef __fp16 h8 __attribute__((ext_vector_type(8)));

__device__ __forceinline__ float hdot4(h4 a, h4 b, float c) {
    const h2 a0 = __builtin_shufflevector(a, a, 0, 1);
    const h2 a1 = __builtin_shufflevector(a, a, 2, 3);
    const h2 b0 = __builtin_shufflevector(b, b, 0, 1);
    const h2 b1 = __builtin_shufflevector(b, b, 2, 3);
    return __builtin_amdgcn_fdot2(a1, b1, __builtin_amdgcn_fdot2(a0, b0, c, false), false);
}

__global__ __launch_bounds__(1024) void bin_kernel(const int* __restrict__ keys, int N,
                                                   int NBW, int* __restrict__ sorted) {
    __shared__ int hist[NE], offs[NE], cur[NE];
    __shared__ int runTot;
    const int t = threadIdx.x;
    if (t < NE) { hist[t] = 0; cur[t] = 0; }
    __syncthreads();
    for (int i = t; i < N; i += 1024) atomicAdd(&hist[keys[i]], 1);
    __syncthreads();
    if (t == 0) {
        int run = 0;
        for (int e = 0; e < NE; ++e) { offs[e] = run; run += (hist[e] + NW - 1) & ~(NW - 1); }
        runTot = run;
    }
    __syncthreads();
    for (int i = t; i < N; i += 1024) {
        const int e = keys[i];
        sorted[offs[e] + atomicAdd(&cur[e], 1)] = i;
    }
    {   // pad fill: expert e = t>>6, lane l = t&63 covers pad (< NW=32 < 64)
        const int e = t >> 6, l = t & 63;
        const int cnt = hist[e];
        const int padded = (cnt + NW - 1) & ~(NW - 1);
        if (l < padded - cnt) sorted[offs[e] + cnt + l] = -1;
    }
    for (int i = runTot + t; i < NBW; i += 1024) sorted[i] = -1;
}

// compile-time-folded zero-padded x access
#define XEL(R,C) (((R) < 0 || (R) > 7 || (C) < 0 || (C) > 7) ? 0.f : xv[(R)&7][(C)&7])

__global__ __launch_bounds__(256, 4) void ae_main(
    const float* __restrict__ x,
    const int*   __restrict__ keys,
    const float* __restrict__ conv_mask,
    const float* __restrict__ enc_conv_w,
    const float* __restrict__ enc_dense_w,
    const float* __restrict__ enc_dense_b,
    const float* __restrict__ dec_dense_w,
    const float* __restrict__ dec_dense_b,
    const float* __restrict__ dec_tconv_w,
    const float* __restrict__ dec_tconv_b,
    const int*   __restrict__ sorted,
    float* __restrict__ out)
{
    const int t = threadIdx.x;
    const int chunk = blockIdx.x / NG;
    const int g = blockIdx.x - chunk * NG;

    __shared__ __attribute__((aligned(16))) __half yt[NW * YW]; // y in fp16 (9.5 KB)
    __shared__ __attribute__((aligned(16))) h2 ews2[640];       // enc w fp16, (pr*8+ch)*20 + o*2+jj
    __shared__ __attribute__((aligned(16))) h2 dws2[512];       // dec w fp16, (p*8+ch)*4 + oo
    __shared__ __attribute__((aligned(16))) h2 wtr2[48];        // tconv w fp16 [tap][hc][chpair]; taps 9..11 = 0
    __shared__ __attribute__((aligned(16))) float wcs[72];      // masked conv w [tap*8+ch]
    __shared__ float dbs[128];                                  // dec bias [p*8+ch]
    __shared__ float ebs[8];

    const int* chunkIds = sorted + chunk * NW;
    const int i0 = chunkIds[0];
    if (i0 < 0) return;
    const int k = keys[i0];

    const int w = t >> 3, ch = t & 7;
    const int idw = chunkIds[w];
    const int idr = (idw < 0) ? i0 : idw;

    // ---- x rows -> registers: 16 independent loads issued before staging ----
    const float* xg = x + (size_t)idr * 896 + g * 64;
    float xv[8][8];
    #pragma unroll
    for (int r = 0; r < 8; ++r) {
        const float4 a = *(const float4*)(xg + r * 8);
        const float4 b = *(const float4*)(xg + r * 8 + 4);
        xv[r][0]=a.x; xv[r][1]=a.y; xv[r][2]=a.z; xv[r][3]=a.w;
        xv[r][4]=b.x; xv[r][5]=b.y; xv[r][6]=b.z; xv[r][7]=b.w;
    }

    // ---- stage weights into LDS (coalesced), dense + tconv weights packed fp16 ----
    const size_t wg1024 = (size_t)(k * NG + g) * 1024;
    {   // ews: thread t <-> (o = t>>5, ch = (t>>2)&7, pr = t&3), 4 floats each
        const float4 w4 = *(const float4*)(enc_dense_w + wg1024 + 4 * t);
        const int o = t >> 5, c2 = (t >> 2) & 7, pr = t & 3;
        const int base = (pr * 8 + c2) * 20 + o * 2;
        ews2[base]     = __builtin_amdgcn_cvt_pkrtz(w4.x, w4.y);
        ews2[base + 1] = __builtin_amdgcn_cvt_pkrtz(w4.z, w4.w);
    }
    if (t < 128) {  // dws: row f = t (= ch*16+p), 8 floats -> 4 h2 (b128 store)
        const float4 a = *(const float4*)(dec_dense_w + wg1024 + 8 * t);
        const float4 b = *(const float4*)(dec_dense_w + wg1024 + 8 * t + 4);
        const int c2 = t >> 4, p = t & 15;
        h2* dst = &dws2[(p * 8 + c2) * 4];
        dst[0] = __builtin_amdgcn_cvt_pkrtz(a.x, a.y);
        dst[1] = __builtin_amdgcn_cvt_pkrtz(a.z, a.w);
        dst[2] = __builtin_amdgcn_cvt_pkrtz(b.x, b.y);
        dst[3] = __builtin_amdgcn_cvt_pkrtz(b.z, b.w);
    } else if (t < 200) {
        const int i = t - 128, c2 = i / 9, tap = i - c2 * 9;
        wcs[tap * 8 + c2] = enc_conv_w[(size_t)k * 1008 + (g * 8 + c2) * 9 + tap] * conv_mask[tap];
    } else if (t < 208) {
        ebs[t - 200] = enc_dense_b[(size_t)k * 112 + g * 8 + (t - 200)];
    } else if (t < 256) {
        const int i = t - 208, tap = i >> 2, j = i & 3;    // 48 threads: taps 0..11
        h2 v = (h2)(__fp16)0.f;
        if (tap < 9) {
            const float wa = dec_tconv_w[(size_t)k * 1008 + (g * 8 + 2*j) * 9 + tap];
            const float wb = dec_tconv_w[(size_t)k * 1008 + (g * 8 + 2*j + 1) * 9 + tap];
            v = __builtin_amdgcn_cvt_pkrtz(wa, wb);
        }
        wtr2[tap * 4 + j] = v;
    }
    if (t < 128) {
        dbs[(t & 15) * 8 + (t >> 4)] = dec_dense_b[(size_t)k * 1792 + g * 128 + t];
    }
    __syncthreads();

    // ---- P1+P2 fused: conv(7 taps)+ReLU+maxpool -> enc GEMV partials (fdot2) ----
    const float w0 = wcs[0*8+ch], w1 = wcs[1*8+ch], w3 = wcs[3*8+ch], w4 = wcs[4*8+ch],
                w5 = wcs[5*8+ch], w7 = wcs[7*8+ch], w8 = wcs[8*8+ch];
    float part[8] = {0.f,0.f,0.f,0.f,0.f,0.f,0.f,0.f};
    #pragma unroll
    for (int pr = 0; pr < 4; ++pr) {
        float res[4];
        #pragma unroll
        for (int pc = 0; pc < 4; ++pc) {
            float mx = 0.f;
            #pragma unroll
            for (int rl = 0; rl < 2; ++rl) {
                #pragma unroll
                for (int cl = 0; cl < 2; ++cl) {
                    const int ir = 2*pr + rl, jc = 2*pc + cl;
                    const float s = w0*XEL(ir-1,jc-1) + w1*XEL(ir-1,jc)
                                  + w3*XEL(ir,jc-1)  + w4*XEL(ir,jc) + w5*XEL(ir,jc+1)
                                  + w7*XEL(ir+1,jc)  + w8*XEL(ir+1,jc+1);
                    mx = fmaxf(mx, s);
                }
            }
            res[pc] = mx;
        }
        const h2 ra = __builtin_amdgcn_cvt_pkrtz(res[0], res[1]);
        const h2 rb = __builtin_amdgcn_cvt_pkrtz(res[2], res[3]);
        const h2* eb2 = &ews2[(pr * 8 + ch) * 20];
        #pragma unroll
        for (int q = 0; q < 4; ++q) {
            const h8 v = *(const h8*)(eb2 + q * 4);      // o=2q (jj0,jj1), o=2q+1 (jj0,jj1)
            const h2 a0 = __builtin_shufflevector(v, v, 0, 1);
            const h2 a1 = __builtin_shufflevector(v, v, 2, 3);
            const h2 b0 = __builtin_shufflevector(v, v, 4, 5);
            const h2 b1 = __builtin_shufflevector(v, v, 6, 7);
            part[2*q]   = __builtin_amdgcn_fdot2(rb, a1, __builtin_amdgcn_fdot2(ra, a0, part[2*q],   false), false);
            part[2*q+1] = __builtin_amdgcn_fdot2(rb, b1, __builtin_amdgcn_fdot2(ra, b0, part[2*q+1], false), false);
        }
    }

    // ---- reduce across the 8 channel lanes; z in registers ----
    float z[8];
    #pragma unroll
    for (int o = 0; o < 8; ++o) {
        float v = part[o];
        v += __shfl_xor(v, 1);
        v += __shfl_xor(v, 2);
        v += __shfl_xor(v, 4);
        z[o] = fmaxf(v + ebs[o], 0.f);
    }
    const h2 z01 = __builtin_amdgcn_cvt_pkrtz(z[0], z[1]);
    const h2 z23 = __builtin_amdgcn_cvt_pkrtz(z[2], z[3]);
    const h2 z45 = __builtin_amdgcn_cvt_pkrtz(z[4], z[5]);
    const h2 z67 = __builtin_amdgcn_cvt_pkrtz(z[6], z[7]);

    // ---- P3: y = relu(decW . z + b) -> LDS fp16 [w][pi*40 + pj*8 + ch] ----
    __half* yw_ = yt + w * YW;
    #pragma unroll
    for (int p = 0; p < 16; ++p) {
        const h8 v = *(const h8*)(&dws2[(p * 8 + ch) * 4]);
        const h2 v0 = __builtin_shufflevector(v, v, 0, 1);
        const h2 v1 = __builtin_shufflevector(v, v, 2, 3);
        const h2 v2 = __builtin_shufflevector(v, v, 4, 5);
        const h2 v3 = __builtin_shufflevector(v, v, 6, 7);
        float acc = dbs[p * 8 + ch];
        acc = __builtin_amdgcn_fdot2(z01, v0, acc, false);
        acc = __builtin_amdgcn_fdot2(z23, v1, acc, false);
        acc = __builtin_amdgcn_fdot2(z45, v2, acc, false);
        acc = __builtin_amdgcn_fdot2(z67, v3, acc, false);
        yw_[(p >> 2) * 40 + (p & 3) * 8 + ch] = __float2half(fmaxf(acc, 0.f));
    }
    // P4 reads only this wave's own y rows (threads w*8..w*8+7 share a wave):
    // drain our LDS writes, no block barrier needed.
    asm volatile("s_waitcnt lgkmcnt(0)" ::: "memory");

    // ---- P4: ConvTranspose2d via fp16 fdot2; thread (w, oi=ch) -> one out row ----
    const int oi = ch;
    int iA, rA, iB, rB;
    if ((oi & 1) == 0) { iA = oi >> 1; rA = 3; iB = 0; rB = 9; }
    else { iA = (oi - 1) >> 1; rA = 6;
           if (oi < 7) { iB = (oi + 1) >> 1; rB = 0; } else { iB = 0; rB = 9; } }
    const float bias = dec_tconv_b[k * NG + g];
    const __fp16* ywh = (const __fp16*)(yt) + w * YW;

    // y tiles as h8 (b128, 16B-aligned), sliced per hc
    h8 yAv[4], yBv[4];
    #pragma unroll
    for (int j = 0; j < 4; ++j) {
        yAv[j] = *(const h8*)(ywh + iA * 40 + j * 8);
        yBv[j] = *(const h8*)(ywh + iB * 40 + j * 8);
    }
    float acc[8] = {0.f,0.f,0.f,0.f,0.f,0.f,0.f,0.f};
    #pragma unroll
    for (int hc = 0; hc < 2; ++hc) {
        const h4 wA0 = *(const h4*)(wtr2 + (rA + 0) * 4 + hc * 2);
        const h4 wA1 = *(const h4*)(wtr2 + (rA + 1) * 4 + hc * 2);
        const h4 wA2 = *(const h4*)(wtr2 + (rA + 2) * 4 + hc * 2);
        const h4 wB0 = *(const h4*)(wtr2 + (rB + 0) * 4 + hc * 2);
        const h4 wB1 = *(const h4*)(wtr2 + (rB + 1) * 4 + hc * 2);
        const h4 wB2 = *(const h4*)(wtr2 + (rB + 2) * 4 + hc * 2);
        h4 yA[4], yB[4];
        #pragma unroll
        for (int j = 0; j < 4; ++j) {
            yA[j] = hc ? __builtin_shufflevector(yAv[j], yAv[j], 4, 5, 6, 7)
                       : __builtin_shufflevector(yAv[j], yAv[j], 0, 1, 2, 3);
            yB[j] = hc ? __builtin_shufflevector(yBv[j], yBv[j], 4, 5, 6, 7)
                       : __builtin_shufflevector(yBv[j], yBv[j], 0, 1, 2, 3);
        }
        acc[0] = hdot4(wB1, yB[0], hdot4(wA1, yA[0], acc[0]));
        acc[1] = hdot4(wB0, yB[1], hdot4(wB2, yB[0],
                 hdot4(wA0, yA[1], hdot4(wA2, yA[0], acc[1]))));
        acc[2] = hdot4(wB1, yB[1], hdot4(wA1, yA[1], acc[2]));
        acc[3] = hdot4(wB0, yB[2], hdot4(wB2, yB[1],
                 hdot4(wA0, yA[2], hdot4(wA2, yA[1], acc[3]))));
        acc[4] = hdot4(wB1, yB[2], hdot4(wA1, yA[2], acc[4]));
        acc[5] = hdot4(wB0, yB[3], hdot4(wB2, yB[2],
                 hdot4(wA0, yA[3], hdot4(wA2, yA[2], acc[5]))));
        acc[6] = hdot4(wB1, yB[3], hdot4(wA1, yA[3], acc[6]));
        acc[7] = hdot4(wB2, yB[3], hdot4(wA2, yA[3], acc[7]));
    }
    if (idw >= 0) {
        float* og = out + (size_t)idw * 896 + g * 64 + oi * 8;
        *(float4*)(og)     = make_float4(fmaxf(acc[0]+bias,0.f), fmaxf(acc[1]+bias,0.f),
                                         fmaxf(acc[2]+bias,0.f), fmaxf(acc[3]+bias,0.f));
        *(float4*)(og + 4) = make_float4(fmaxf(acc[4]+bias,0.f), fmaxf(acc[5]+bias,0.f),
                                         fmaxf(acc[6]+bias,0.f), fmaxf(acc[7]+bias,0.f));
    }
}

extern "C" void kernel_launch(void* const* d_in, const int* in_sizes, int n_in,
                              void* d_out, int out_size, void* d_ws, size_t ws_size,
                              hipStream_t stream) {
    const float* x            = (const float*)d_in[0];
    const int*   keys         = (const int*)d_in[1];
    const float* conv_mask    = (const float*)d_in[2];
    const float* enc_conv_w   = (const float*)d_in[3];
    const float* enc_dense_w  = (const float*)d_in[4];
    const float* enc_dense_b  = (const float*)d_in[5];
    const float* dec_dense_w  = (const float*)d_in[6];
    const float* dec_dense_b  = (const float*)d_in[7];
    const float* dec_tconv_w  = (const float*)d_in[8];
    const float* dec_tconv_b  = (const float*)d_in[9];
    float* out = (float*)d_out;

    const int N = in_sizes[0] / (NG * 64);                   // 4096
    const int CHUNKS = (N + NE * (NW - 1)) / NW + 1;         // 144
    int* sorted = (int*)d_ws;

    bin_kernel<<<1, 1024, 0, stream>>>(keys, N, CHUNKS * NW, sorted);
    ae_main<<<CHUNKS * NG, 256, 0, stream>>>(
        x, keys, conv_mask, enc_conv_w, enc_dense_w, enc_dense_b,
        dec_dense_w, dec_dense_b, dec_tconv_w, dec_tconv_b, sorted, out);
}